// Round 1
// baseline (719.116 us; speedup 1.0000x reference)
//
#include <hip/hip_runtime.h>
#include <hip/hip_bf16.h>

// Upsample_conv_2d fused as one implicit GEMM:
//   M = 4*128*128 (b,ro,so), K = 9*256 (tap,ci), N = 4*256 (parity,co)
// out[b, 2ro+pr, 2so+ps, co] = sum_{dy,dx,ci} K[pr,ps,dy,dx,ci,co] * x[b,ro+dy-1,so+dx-1,ci] + bias[co]

typedef __attribute__((ext_vector_type(8))) __bf16 bf16x8;
typedef __attribute__((ext_vector_type(4))) float floatx4;

#define XP_ELEMS (4*130*130*256)          // padded bf16 x
#define XP_BYTES (XP_ELEMS*2)             // 34,611,200
#define KT_ELEMS (1024*2304)              // transposed fused weights, bf16

__device__ __forceinline__ void gl_lds16(const void* g, void* l) {
  __builtin_amdgcn_global_load_lds((const __attribute__((address_space(1))) void*)g,
                                   (__attribute__((address_space(3))) void*)l,
                                   16, 0, 0);
}

// x [4][128][128][256] f32 -> xp [4][130][130][256] bf16, zero border (pad 1)
__global__ void pad_cast_kernel(const float* __restrict__ x,
                                __hip_bfloat16* __restrict__ xp) {
  int t = blockIdx.x * 256 + threadIdx.x;      // one thread per 8 channels
  if (t >= 4*130*130*32) return;
  int c8  = (t & 31) << 3;
  int pix = t >> 5;
  int wc  = pix % 130;
  int tmp = pix / 130;
  int hr  = tmp % 130;
  int b   = tmp / 130;
  float vals[8] = {0.f,0.f,0.f,0.f,0.f,0.f,0.f,0.f};
  if (hr >= 1 && hr <= 128 && wc >= 1 && wc <= 128) {
    const float* s = x + (size_t)(((b*128 + (hr-1))*128 + (wc-1))*256 + c8);
    const float4 a = *(const float4*)s;
    const float4 c = *(const float4*)(s + 4);
    vals[0]=a.x; vals[1]=a.y; vals[2]=a.z; vals[3]=a.w;
    vals[4]=c.x; vals[5]=c.y; vals[6]=c.z; vals[7]=c.w;
  }
  __align__(16) __hip_bfloat16 o[8];
  #pragma unroll
  for (int i = 0; i < 8; ++i) o[i] = __float2bfloat16(vals[i]);
  *reinterpret_cast<uint4*>(xp + (size_t)t*8) = *reinterpret_cast<const uint4*>(o);
}

// w [3][3][256][256] f32 -> kt [n=1024][k=2304] bf16 (n-major so GEMM B-tile is k-contiguous)
// n = (pr*2+ps)*256 + co ; k = (dy*3+dx)*256 + ci
__global__ void make_kt_kernel(const float* __restrict__ w,
                               __hip_bfloat16* __restrict__ kt) {
  int t = blockIdx.x * 256 + threadIdx.x;
  if (t >= KT_ELEMS) return;
  int k = t % 2304;
  int n = t / 2304;
  int par = n >> 8, co = n & 255;
  int pr = par >> 1, ps = par & 1;
  int tap = k >> 8, ci = k & 255;
  int dy = tap / 3, dx = tap - dy*3;
  // from f=(1,3,3,1): per-parity per-offset tap coefficients (x 1/4 each dim)
  const float Atab[2][3][3] = {
    {{3.f,1.f,0.f},{1.f,3.f,3.f},{0.f,0.f,1.f}},   // pr=0 (even output rows)
    {{1.f,0.f,0.f},{3.f,3.f,1.f},{0.f,1.f,3.f}}    // pr=1 (odd output rows)
  };
  float s = 0.f;
  #pragma unroll
  for (int i = 0; i < 3; ++i) {
    float ay = Atab[pr][dy][i];
    #pragma unroll
    for (int j = 0; j < 3; ++j) {
      float ax = Atab[ps][dx][j];
      float c = ay * ax;
      if (c != 0.f)
        s += c * w[(size_t)(((i*3 + j)*256 + ci))*256 + co];
    }
  }
  kt[t] = __float2bfloat16(s * 0.0625f);   // /16 = (1/4)^2 FIR normalization
}

// GEMM: 128x128 tile per block (256 thr = 4 waves, 2x2 wave grid, 64x64/wave),
// BK=32, 16x16x32 bf16 MFMA, global_load_lds(16B) staging, m97-style 2-barrier K-loop.
__global__ __launch_bounds__(256) void gemm_kernel(
    const __hip_bfloat16* __restrict__ xp,   // [4][130][130][256]
    const __hip_bfloat16* __restrict__ kt,   // [1024][2304]
    const float* __restrict__ bias,          // [256]
    float* __restrict__ out)                 // [4][256][256][256]
{
  __shared__ __align__(16) __hip_bfloat16 sA[128*32];  // [m][k] 8KB
  __shared__ __align__(16) __hip_bfloat16 sB[128*32];  // [n][k] 8KB

  const int tid = threadIdx.x;
  const int bid = blockIdx.x;
  const int mt  = bid >> 3;      // 512 m-tiles: (b,ro)
  const int nt  = bid & 7;       // 8 n-tiles
  const int b   = mt >> 7;
  const int ro  = mt & 127;
  const int n0  = nt << 7;

  const int wv   = tid >> 6;
  const int ln   = tid & 63;
  const int lm   = ln & 15;
  const int quad = ln >> 4;
  const int wm   = wv >> 1;      // 0..1
  const int wn   = wv & 1;

  const int sr    = tid >> 2;         // staging row 0..63 (chunk set 0)
  const int inner = (tid & 3) << 3;   // 0,8,16,24 bf16 within row

  // wave-uniform LDS destinations (HW adds lane*16B)
  __hip_bfloat16* lA0 = sA + (wv*64)*8;
  __hip_bfloat16* lA1 = sA + (wv*64 + 256)*8;
  __hip_bfloat16* lB0 = sB + (wv*64)*8;
  __hip_bfloat16* lB1 = sB + (wv*64 + 256)*8;

  floatx4 acc[4][4];
  #pragma unroll
  for (int i = 0; i < 4; ++i)
    #pragma unroll
    for (int j = 0; j < 4; ++j)
      acc[i][j] = (floatx4){0.f, 0.f, 0.f, 0.f};

  const __hip_bfloat16* xb = xp + (size_t)(b*130)*130*256;

  for (int ks = 0; ks < 72; ++ks) {
    const int tap = ks >> 3;            // 0..8 -> (dy,dx)
    const int ci0 = (ks & 7) << 5;      // 0..224
    const int dy  = tap / 3;
    const int dx  = tap - dy*3;
    const int k0  = ks << 5;

    const __hip_bfloat16* gA = xb + (size_t)((ro + dy)*130 + dx + sr)*256 + ci0 + inner;
    gl_lds16(gA,            lA0);
    gl_lds16(gA + 64*256,   lA1);
    const __hip_bfloat16* gB = kt + (size_t)(n0 + sr)*2304 + k0 + inner;
    gl_lds16(gB,            lB0);
    gl_lds16(gB + 64*2304,  lB1);

    __syncthreads();

    bf16x8 af[4], bfr[4];
    #pragma unroll
    for (int i = 0; i < 4; ++i)
      af[i]  = *reinterpret_cast<const bf16x8*>(sA + (wm*64 + i*16 + lm)*32 + quad*8);
    #pragma unroll
    for (int i = 0; i < 4; ++i)
      bfr[i] = *reinterpret_cast<const bf16x8*>(sB + (wn*64 + i*16 + lm)*32 + quad*8);

    #pragma unroll
    for (int mi = 0; mi < 4; ++mi)
      #pragma unroll
      for (int ni = 0; ni < 4; ++ni)
        acc[mi][ni] = __builtin_amdgcn_mfma_f32_16x16x32_bf16(af[mi], bfr[ni], acc[mi][ni], 0, 0, 0);

    __syncthreads();
  }

  // epilogue: C/D layout col=lane&15 (n), row=quad*4+reg (m); m==so, n->(pr,ps,co)
  #pragma unroll
  for (int ni = 0; ni < 4; ++ni) {
    const int n   = n0 + wn*64 + ni*16 + lm;
    const int par = n >> 8;
    const int co  = n & 255;
    const int pr  = par >> 1;
    const int ps  = par & 1;
    const float bv = bias[co];
    const int rowo = b*256 + 2*ro + pr;
    #pragma unroll
    for (int mi = 0; mi < 4; ++mi) {
      const int so_b = wm*64 + mi*16 + (quad << 2);
      #pragma unroll
      for (int r = 0; r < 4; ++r) {
        const int so = so_b + r;
        out[((size_t)rowo*256 + (2*so + ps))*256 + co] = acc[mi][ni][r] + bv;
      }
    }
  }
}

extern "C" void kernel_launch(void* const* d_in, const int* in_sizes, int n_in,
                              void* d_out, int out_size, void* d_ws, size_t ws_size,
                              hipStream_t stream) {
  const float* x    = (const float*)d_in[0];   // (4,128,128,256)
  const float* w    = (const float*)d_in[1];   // (3,3,256,256)
  const float* bias = (const float*)d_in[2];   // (256,)
  float* out = (float*)d_out;                  // (4,256,256,256)

  __hip_bfloat16* xp = (__hip_bfloat16*)d_ws;
  __hip_bfloat16* kt = (__hip_bfloat16*)((char*)d_ws + XP_BYTES);

  pad_cast_kernel<<<(4*130*130*32 + 255)/256, 256, 0, stream>>>(x, xp);
  make_kt_kernel<<<(KT_ELEMS + 255)/256, 256, 0, stream>>>(w, kt);
  gemm_kernel<<<4096, 256, 0, stream>>>(xp, kt, bias, out);
}

// Round 2
// 638.451 us; speedup vs baseline: 1.1263x; 1.1263x over previous
//
#include <hip/hip_runtime.h>
#include <hip/hip_bf16.h>

// Upsample_conv_2d fused as one implicit GEMM:
//   M = 4*128*128 (b,ro,so), K = 9*256 (tap,ci), N = 4*256 (parity,co)
// out[b, 2ro+pr, 2so+ps, co] = sum_{dy,dx,ci} K[pr,ps,dy,dx,ci,co] * x[b,ro+dy-1,so+dx-1,ci] + bias[co]

typedef __attribute__((ext_vector_type(8))) __bf16 bf16x8;
typedef __attribute__((ext_vector_type(4))) float floatx4;

#define XP_ELEMS (4*130*130*256)          // padded bf16 x
#define XP_BYTES (XP_ELEMS*2)             // 34,611,200
#define KT_ELEMS (1024*2304)              // transposed fused weights, bf16

__device__ __forceinline__ void gl_lds16(const void* g, void* l) {
  __builtin_amdgcn_global_load_lds((const __attribute__((address_space(1))) void*)g,
                                   (__attribute__((address_space(3))) void*)l,
                                   16, 0, 0);
}

// x [4][128][128][256] f32 -> xp [4][130][130][256] bf16, zero border (pad 1)
__global__ void pad_cast_kernel(const float* __restrict__ x,
                                __hip_bfloat16* __restrict__ xp) {
  int t = blockIdx.x * 256 + threadIdx.x;      // one thread per 8 channels
  if (t >= 4*130*130*32) return;
  int c8  = (t & 31) << 3;
  int pix = t >> 5;
  int wc  = pix % 130;
  int tmp = pix / 130;
  int hr  = tmp % 130;
  int b   = tmp / 130;
  float vals[8] = {0.f,0.f,0.f,0.f,0.f,0.f,0.f,0.f};
  if (hr >= 1 && hr <= 128 && wc >= 1 && wc <= 128) {
    const float* s = x + (size_t)(((b*128 + (hr-1))*128 + (wc-1))*256 + c8);
    const float4 a = *(const float4*)s;
    const float4 c = *(const float4*)(s + 4);
    vals[0]=a.x; vals[1]=a.y; vals[2]=a.z; vals[3]=a.w;
    vals[4]=c.x; vals[5]=c.y; vals[6]=c.z; vals[7]=c.w;
  }
  __align__(16) __hip_bfloat16 o[8];
  #pragma unroll
  for (int i = 0; i < 8; ++i) o[i] = __float2bfloat16(vals[i]);
  *reinterpret_cast<uint4*>(xp + (size_t)t*8) = *reinterpret_cast<const uint4*>(o);
}

// w [3][3][256][256] f32 -> kt [n=1024][k=2304] bf16 (n-major so GEMM B-tile is k-contiguous)
// n = (pr*2+ps)*256 + co ; k = (dy*3+dx)*256 + ci
// Grid: 288 blocks = 4 par * 9 tap * 8 ci-blocks; thread = co. Coalesced reads over co.
__global__ void make_kt_kernel(const float* __restrict__ w,
                               __hip_bfloat16* __restrict__ kt) {
  const int b     = blockIdx.x;
  const int ciblk = b & 7;
  const int tap   = (b >> 3) % 9;
  const int par   = b / 72;
  const int co    = threadIdx.x;
  const int pr = par >> 1, ps = par & 1;
  const int dy = tap / 3, dx = tap - dy*3;

  const float Atab[2][3][3] = {
    {{3.f,1.f,0.f},{1.f,3.f,3.f},{0.f,0.f,1.f}},   // even output parity
    {{1.f,0.f,0.f},{3.f,3.f,1.f},{0.f,1.f,3.f}}    // odd output parity
  };

  float s[32];
  #pragma unroll
  for (int u = 0; u < 32; ++u) s[u] = 0.f;

  for (int i = 0; i < 3; ++i) {
    const float ay = Atab[pr][dy][i];
    if (ay == 0.f) continue;
    for (int j = 0; j < 3; ++j) {
      const float c = ay * Atab[ps][dx][j];
      if (c == 0.f) continue;
      const float* wp = w + ((size_t)(i*3 + j)*256 + ciblk*32)*256 + co;
      #pragma unroll
      for (int u = 0; u < 32; ++u)
        s[u] += c * wp[(size_t)u*256];
    }
  }

  __align__(16) __hip_bfloat16 o[32];
  #pragma unroll
  for (int u = 0; u < 32; ++u) o[u] = __float2bfloat16(s[u] * 0.0625f);
  __hip_bfloat16* dst = kt + (size_t)(par*256 + co)*2304 + tap*256 + ciblk*32;
  #pragma unroll
  for (int v = 0; v < 4; ++v)
    reinterpret_cast<uint4*>(dst)[v] = reinterpret_cast<const uint4*>(o)[v];
}

// GEMM: 128x128 tile per block (256 thr = 4 waves, 2x2 wave grid, 64x64/wave),
// BK=32, 16x16x32 bf16 MFMA, global_load_lds(16B) staging.
// XCD-aware bid swizzle: the 8 n-tiles sharing one A-tile are consecutive on one XCD.
// XOR LDS swizzle (global-side chunk permute) kills ds_read_b128 bank conflicts.
__global__ __launch_bounds__(256) void gemm_kernel(
    const __hip_bfloat16* __restrict__ xp,   // [4][130][130][256]
    const __hip_bfloat16* __restrict__ kt,   // [1024][2304]
    const float* __restrict__ bias,          // [256]
    float* __restrict__ out)                 // [4][256][256][256]
{
  __shared__ __align__(16) __hip_bfloat16 sA[128*32];  // [m][k] 8KB, xor-swizzled chunks
  __shared__ __align__(16) __hip_bfloat16 sB[128*32];  // [n][k] 8KB

  const int tid = threadIdx.x;
  const int bid = blockIdx.x;
  // XCD swizzle: bid%8 selects XCD; keep same-mt blocks adjacent per XCD.
  const int mt  = (bid & 7) + ((bid >> 6) << 3);   // 0..511 : (b,ro)
  const int nt  = (bid >> 3) & 7;                  // 0..7
  const int b   = mt >> 7;
  const int ro  = mt & 127;
  const int n0  = nt << 7;

  const int wv   = tid >> 6;
  const int ln   = tid & 63;
  const int lm   = ln & 15;
  const int quad = ln >> 4;
  const int wm   = wv >> 1;      // 0..1
  const int wn   = wv & 1;

  const int sr    = tid >> 2;                              // staging row 0..63
  const int inner = (((tid & 3) ^ ((sr >> 1) & 3)) << 3);  // swizzled 8-elem chunk

  // wave-uniform LDS destinations (HW adds lane*16B)
  __hip_bfloat16* lA0 = sA + (wv*64)*8;
  __hip_bfloat16* lA1 = sA + (wv*64 + 256)*8;
  __hip_bfloat16* lB0 = sB + (wv*64)*8;
  __hip_bfloat16* lB1 = sB + (wv*64 + 256)*8;

  floatx4 acc[4][4];
  #pragma unroll
  for (int i = 0; i < 4; ++i)
    #pragma unroll
    for (int j = 0; j < 4; ++j)
      acc[i][j] = (floatx4){0.f, 0.f, 0.f, 0.f};

  const __hip_bfloat16* xb = xp + (size_t)(b*130)*130*256;
  // fragment-read swizzled chunk offset (elements): quad ^ ((row>>1)&3), row-bit4+ drops out
  const int cs = ((quad ^ ((lm >> 1) & 3)) << 3);

  for (int ks = 0; ks < 72; ++ks) {
    const int tap = ks >> 3;            // 0..8 -> (dy,dx)
    const int ci0 = (ks & 7) << 5;      // 0..224
    const int dy  = tap / 3;
    const int dx  = tap - dy*3;
    const int k0  = ks << 5;

    const __hip_bfloat16* gA = xb + (size_t)((ro + dy)*130 + dx + sr)*256 + ci0 + inner;
    gl_lds16(gA,            lA0);
    gl_lds16(gA + 64*256,   lA1);
    const __hip_bfloat16* gB = kt + (size_t)(n0 + sr)*2304 + k0 + inner;
    gl_lds16(gB,            lB0);
    gl_lds16(gB + 64*2304,  lB1);

    __syncthreads();

    bf16x8 af[4], bfr[4];
    #pragma unroll
    for (int i = 0; i < 4; ++i)
      af[i]  = *reinterpret_cast<const bf16x8*>(sA + (wm*64 + i*16 + lm)*32 + cs);
    #pragma unroll
    for (int i = 0; i < 4; ++i)
      bfr[i] = *reinterpret_cast<const bf16x8*>(sB + (wn*64 + i*16 + lm)*32 + cs);

    #pragma unroll
    for (int mi = 0; mi < 4; ++mi)
      #pragma unroll
      for (int ni = 0; ni < 4; ++ni)
        acc[mi][ni] = __builtin_amdgcn_mfma_f32_16x16x32_bf16(af[mi], bfr[ni], acc[mi][ni], 0, 0, 0);

    __syncthreads();
  }

  // epilogue: C/D layout col=lane&15 (n), row=quad*4+reg (m); m==so, n->(pr,ps,co)
  #pragma unroll
  for (int ni = 0; ni < 4; ++ni) {
    const int n   = n0 + wn*64 + ni*16 + lm;
    const int par = n >> 8;
    const int co  = n & 255;
    const int pr  = par >> 1;
    const int ps  = par & 1;
    const float bv = bias[co];
    const int rowo = b*256 + 2*ro + pr;
    #pragma unroll
    for (int mi = 0; mi < 4; ++mi) {
      const int so_b = wm*64 + mi*16 + (quad << 2);
      #pragma unroll
      for (int r = 0; r < 4; ++r) {
        const int so = so_b + r;
        out[((size_t)rowo*256 + (2*so + ps))*256 + co] = acc[mi][ni][r] + bv;
      }
    }
  }
}

extern "C" void kernel_launch(void* const* d_in, const int* in_sizes, int n_in,
                              void* d_out, int out_size, void* d_ws, size_t ws_size,
                              hipStream_t stream) {
  const float* x    = (const float*)d_in[0];   // (4,128,128,256)
  const float* w    = (const float*)d_in[1];   // (3,3,256,256)
  const float* bias = (const float*)d_in[2];   // (256,)
  float* out = (float*)d_out;                  // (4,256,256,256)

  __hip_bfloat16* xp = (__hip_bfloat16*)d_ws;
  __hip_bfloat16* kt = (__hip_bfloat16*)((char*)d_ws + XP_BYTES);

  pad_cast_kernel<<<(4*130*130*32 + 255)/256, 256, 0, stream>>>(x, xp);
  make_kt_kernel<<<288, 256, 0, stream>>>(w, kt);
  gemm_kernel<<<4096, 256, 0, stream>>>(xp, kt, bias, out);
}

// Round 3
// 585.627 us; speedup vs baseline: 1.2279x; 1.0902x over previous
//
#include <hip/hip_runtime.h>
#include <hip/hip_bf16.h>

// Two-stage decomposition of upsample_conv_2d:
//   stage 1: u = conv_transpose(x, w) (stride 2, VALID) on the 257x257 upsampled
//            grid, computed as 4 parity GEMMs with K in {1024,512,512,256}
//            (77.5 GFLOP vs 309 GFLOP fused), u stored bf16 with 1-pixel zero border.
//   stage 2: out = FIR (1,3,3,1)x(1,3,3,1) (1/16 folded into stage-1 weights) + bias.
// Parity algebra (verified vs fused Atab, both parities + DC gain 2304):
//   u[2q]   = w2 x[q] + w0 x[q-1]   (per dim, flipped-w indexing)
//   u[2q+1] = w1 x[q]
//   out[r]  = sum_a f[a] u[r+a-1],  f = (1,3,3,1)

typedef __attribute__((ext_vector_type(8))) __bf16 bf16x8;
typedef __attribute__((ext_vector_type(4))) float floatx4;

#define XP_ELEMS (4*130*130*256)
#define XP_BYTES ((size_t)XP_ELEMS*2)            // 34,611,200
#define U_ELEMS  ((size_t)4*259*259*256)
#define U_BYTES  (U_ELEMS*2)                     // 137,381,888
#define WQ_ELEMS 589824
#define WQ_BYTES ((size_t)WQ_ELEMS*2)            // 1,179,648
#define NEED_WS  (XP_BYTES + U_BYTES + WQ_BYTES) // 173,172,736
#define KT_ELEMS (1024*2304)

__device__ __forceinline__ void gl_lds16(const void* g, void* l) {
  __builtin_amdgcn_global_load_lds((const __attribute__((address_space(1))) void*)g,
                                   (__attribute__((address_space(3))) void*)l,
                                   16, 0, 0);
}

// ---------------- shared prep: x -> padded bf16 ----------------
__global__ void pad_cast_kernel(const float* __restrict__ x,
                                __hip_bfloat16* __restrict__ xp) {
  int t = blockIdx.x * 256 + threadIdx.x;
  if (t >= 4*130*130*32) return;
  int c8  = (t & 31) << 3;
  int pix = t >> 5;
  int wc  = pix % 130;
  int tmp = pix / 130;
  int hr  = tmp % 130;
  int b   = tmp / 130;
  float vals[8] = {0.f,0.f,0.f,0.f,0.f,0.f,0.f,0.f};
  if (hr >= 1 && hr <= 128 && wc >= 1 && wc <= 128) {
    const float* s = x + (size_t)(((b*128 + (hr-1))*128 + (wc-1))*256 + c8);
    const float4 a = *(const float4*)s;
    const float4 c = *(const float4*)(s + 4);
    vals[0]=a.x; vals[1]=a.y; vals[2]=a.z; vals[3]=a.w;
    vals[4]=c.x; vals[5]=c.y; vals[6]=c.z; vals[7]=c.w;
  }
  __align__(16) __hip_bfloat16 o[8];
  #pragma unroll
  for (int i = 0; i < 8; ++i) o[i] = __float2bfloat16(vals[i]);
  *reinterpret_cast<uint4*>(xp + (size_t)t*8) = *reinterpret_cast<const uint4*>(o);
}

// ---------------- stage-1 weights: wq[e][co][k], k=(tap,ci), 1/16 folded ----------------
__global__ void make_wq_kernel(const float* __restrict__ w,
                               __hip_bfloat16* __restrict__ wq) {
  int t = blockIdx.x * 256 + threadIdx.x;     // < 589824
  int e, off, KE;
  if (t < 262144)      { e=0; off=0;      KE=1024; }
  else if (t < 393216) { e=1; off=262144; KE=512; }
  else if (t < 524288) { e=2; off=393216; KE=512; }
  else                 { e=3; off=524288; KE=256; }
  int rel = t - off;
  int co = rel / KE, k = rel - co*KE;
  int tap = k >> 8, ci = k & 255;
  const int iT[4][4] = {{2,2,0,0},{2,0,0,0},{1,1,0,0},{1,0,0,0}};
  const int jT[4][4] = {{2,0,2,0},{1,1,0,0},{2,0,0,0},{1,0,0,0}};
  int i = iT[e][tap], jx = jT[e][tap];
  float v = w[((size_t)((i*3 + jx)*256 + ci))*256 + co] * 0.0625f;
  wq[t] = __float2bfloat16(v);
}

// ---------------- zero U top row (ty=-1) and left col (tx=-1) ----------------
__global__ void border_zero_kernel(__hip_bfloat16* __restrict__ U) {
  const int bid = blockIdx.x;            // 4 * 517
  const int b = bid / 517, p = bid % 517;
  size_t idx;
  if (p < 259) idx = (((size_t)b*259 + 0)*259 + p)*256;              // top row incl corners
  else         idx = (((size_t)b*259 + (p - 259 + 1))*259 + 0)*256;  // left col rows 1..258
  U[idx + threadIdx.x] = __float2bfloat16(0.f);
}

// ---------------- stage 1: parity GEMMs -> u (bf16) ----------------
template<int E>
__device__ __forceinline__ void stage1_body(const __hip_bfloat16* __restrict__ xp,
                                            const __hip_bfloat16* __restrict__ wq,
                                            __hip_bfloat16* __restrict__ U,
                                            int mt, int nt,
                                            __hip_bfloat16* sA, __hip_bfloat16* sB) {
  constexpr int KE   = (E==0)?1024:(E==3)?256:512;
  constexpr int NIT  = KE/32;
  constexpr int WOFF = (E==0)?0:(E==1)?262144:(E==2)?393216:524288;
  constexpr int EY = E>>1, EX = E&1;
  constexpr int D1 = (E==1) ? -130 : -1;   // tap1 pixel offset (tap0 is 0; taps 2,3 only for E==0)

  const int tid = threadIdx.x;
  const int b   = mt / 131;
  const int mtb = mt - b*131;
  const int n0  = nt << 7;

  const int wv   = tid >> 6;
  const int ln   = tid & 63;
  const int lm   = ln & 15;
  const int quad = ln >> 4;
  const int wm   = wv >> 1;
  const int wn   = wv & 1;

  const int sr    = tid >> 2;
  const int inner = (((tid & 3) ^ ((sr >> 1) & 3)) << 3);

  const int mbase = mtb << 7;
  int ms0 = mbase + sr;       if (ms0 > 16640) ms0 = 16640;
  int ms1 = mbase + sr + 64;  if (ms1 > 16640) ms1 = 16640;
  const int qy0 = ms0 / 129, qx0 = ms0 - qy0*129;
  const int qy1 = ms1 / 129, qx1 = ms1 - qy1*129;
  const int pix0 = (qy0 + 1)*130 + (qx0 + 1);
  const int pix1 = (qy1 + 1)*130 + (qx1 + 1);

  __hip_bfloat16* lA0 = sA + (wv*64)*8;
  __hip_bfloat16* lA1 = sA + (wv*64 + 256)*8;
  __hip_bfloat16* lB0 = sB + (wv*64)*8;
  __hip_bfloat16* lB1 = sB + (wv*64 + 256)*8;

  floatx4 acc[4][4];
  #pragma unroll
  for (int i = 0; i < 4; ++i)
    #pragma unroll
    for (int j = 0; j < 4; ++j)
      acc[i][j] = (floatx4){0.f, 0.f, 0.f, 0.f};

  const __hip_bfloat16* xb  = xp + (size_t)b*130*130*256;
  const __hip_bfloat16* wqe = wq + WOFF;
  const int cs = ((quad ^ ((lm >> 1) & 3)) << 3);

  for (int ks = 0; ks < NIT; ++ks) {
    const int tap = ks >> 3;
    const int ci0 = (ks & 7) << 5;
    const int k0  = ks << 5;
    const int off = (tap == 0) ? 0 : (tap == 1) ? D1 : (tap == 2) ? -130 : -131;

    gl_lds16(xb + (size_t)(pix0 + off)*256 + ci0 + inner, lA0);
    gl_lds16(xb + (size_t)(pix1 + off)*256 + ci0 + inner, lA1);
    gl_lds16(wqe + (size_t)(n0 + sr)*KE      + k0 + inner, lB0);
    gl_lds16(wqe + (size_t)(n0 + sr + 64)*KE + k0 + inner, lB1);

    __syncthreads();

    bf16x8 af[4], bfr[4];
    #pragma unroll
    for (int i = 0; i < 4; ++i)
      af[i]  = *reinterpret_cast<const bf16x8*>(sA + (wm*64 + i*16 + lm)*32 + cs);
    #pragma unroll
    for (int i = 0; i < 4; ++i)
      bfr[i] = *reinterpret_cast<const bf16x8*>(sB + (wn*64 + i*16 + lm)*32 + cs);

    #pragma unroll
    for (int mi = 0; mi < 4; ++mi)
      #pragma unroll
      for (int ni = 0; ni < 4; ++ni)
        acc[mi][ni] = __builtin_amdgcn_mfma_f32_16x16x32_bf16(af[mi], bfr[ni], acc[mi][ni], 0, 0, 0);

    __syncthreads();
  }

  // epilogue: C col=lane&15 -> co, row=quad*4+reg -> m; m -> (qy,qx) -> u pixel
  #pragma unroll
  for (int ni = 0; ni < 4; ++ni) {
    const int co = n0 + wn*64 + ni*16 + lm;
    #pragma unroll
    for (int mi = 0; mi < 4; ++mi) {
      const int ml = wm*64 + mi*16 + (quad << 2);
      #pragma unroll
      for (int r = 0; r < 4; ++r) {
        const int m = mbase + ml + r;
        if (m <= 16640) {
          const int qy = m / 129, qx = m - qy*129;
          const int R = 2*qy + EY + 1, C = 2*qx + EX + 1;
          U[(((size_t)b*259 + R)*259 + C)*256 + co] = __float2bfloat16(acc[mi][ni][r]);
        }
      }
    }
  }
}

__global__ __launch_bounds__(256) void stage1_kernel(const __hip_bfloat16* __restrict__ xp,
                                                     const __hip_bfloat16* __restrict__ wq,
                                                     __hip_bfloat16* __restrict__ U) {
  __shared__ __align__(16) __hip_bfloat16 sA[128*32];
  __shared__ __align__(16) __hip_bfloat16 sB[128*32];
  const int bid = blockIdx.x;
  const int mt = (bid & 7) + ((bid >> 6) << 3);   // same-XCD consecutive bids share mt
  if (mt >= 524) return;
  const int g = (bid >> 3) & 7;
  const int e = g >> 1, nt = g & 1;
  switch (e) {
    case 0: stage1_body<0>(xp, wq, U, mt, nt, sA, sB); break;
    case 1: stage1_body<1>(xp, wq, U, mt, nt, sA, sB); break;
    case 2: stage1_body<2>(xp, wq, U, mt, nt, sA, sB); break;
    default: stage1_body<3>(xp, wq, U, mt, nt, sA, sB); break;
  }
}

// ---------------- stage 2: 16-tap FIR + bias ----------------
// thread: 2x2 out pixels x 8 co from a 5x5 u window (separable (1,3,3,1)).
__global__ __launch_bounds__(256) void fir_kernel(const __hip_bfloat16* __restrict__ U,
                                                  const float* __restrict__ bias,
                                                  float* __restrict__ out) {
  const int bid = blockIdx.x, tid = threadIdx.x;
  const int b = bid >> 11, i = (bid >> 4) & 127, jb = bid & 15;
  const int c8 = tid & 31, jj = tid >> 5;
  const int j = jb*8 + jj, co = c8 << 3;
  const __hip_bfloat16* Ub = U + (((size_t)b*259 + 2*i)*259 + 2*j)*256 + co;

  float ve[5][8], vo[5][8];
  #pragma unroll
  for (int dx = 0; dx < 5; ++dx) {
    float r[5][8];
    #pragma unroll
    for (int dy = 0; dy < 5; ++dy) {
      uint4 q = *reinterpret_cast<const uint4*>(Ub + ((size_t)(dy*259 + dx) << 8));
      const unsigned* w32 = reinterpret_cast<const unsigned*>(&q);
      #pragma unroll
      for (int t = 0; t < 4; ++t) {
        r[dy][2*t]   = __uint_as_float(w32[t] << 16);
        r[dy][2*t+1] = __uint_as_float(w32[t] & 0xffff0000u);
      }
    }
    #pragma unroll
    for (int k = 0; k < 8; ++k) {
      ve[dx][k] = (r[0][k] + r[3][k]) + 3.f*(r[1][k] + r[2][k]);
      vo[dx][k] = (r[1][k] + r[4][k]) + 3.f*(r[2][k] + r[3][k]);
    }
  }
  float bv[8];
  *(float4*)bv     = *(const float4*)(bias + co);
  *(float4*)(bv+4) = *(const float4*)(bias + co + 4);
  float o[4][8];
  #pragma unroll
  for (int k = 0; k < 8; ++k) {
    o[0][k] = (ve[0][k]+ve[3][k]) + 3.f*(ve[1][k]+ve[2][k]) + bv[k];
    o[1][k] = (ve[1][k]+ve[4][k]) + 3.f*(ve[2][k]+ve[3][k]) + bv[k];
    o[2][k] = (vo[0][k]+vo[3][k]) + 3.f*(vo[1][k]+vo[2][k]) + bv[k];
    o[3][k] = (vo[1][k]+vo[4][k]) + 3.f*(vo[2][k]+vo[3][k]) + bv[k];
  }
  #pragma unroll
  for (int pr = 0; pr < 2; ++pr)
    #pragma unroll
    for (int ps = 0; ps < 2; ++ps) {
      float* op = out + (((size_t)(b*256 + 2*i + pr))*256 + (2*j + ps))*256 + co;
      *(float4*)op     = *(float4*)&o[pr*2+ps][0];
      *(float4*)(op+4) = *(float4*)&o[pr*2+ps][4];
    }
}

// ================= fallback (round-2 fused GEMM) if ws too small =================
__global__ void make_kt_kernel(const float* __restrict__ w,
                               __hip_bfloat16* __restrict__ kt) {
  const int bb    = blockIdx.x;
  const int ciblk = bb & 7;
  const int tap   = (bb >> 3) % 9;
  const int par   = bb / 72;
  const int co    = threadIdx.x;
  const int pr = par >> 1, ps = par & 1;
  const int dy = tap / 3, dx = tap - dy*3;
  const float Atab[2][3][3] = {
    {{3.f,1.f,0.f},{1.f,3.f,3.f},{0.f,0.f,1.f}},
    {{1.f,0.f,0.f},{3.f,3.f,1.f},{0.f,1.f,3.f}}
  };
  float s[32];
  #pragma unroll
  for (int u = 0; u < 32; ++u) s[u] = 0.f;
  for (int i = 0; i < 3; ++i) {
    const float ay = Atab[pr][dy][i];
    if (ay == 0.f) continue;
    for (int j = 0; j < 3; ++j) {
      const float c = ay * Atab[ps][dx][j];
      if (c == 0.f) continue;
      const float* wp = w + ((size_t)(i*3 + j)*256 + ciblk*32)*256 + co;
      #pragma unroll
      for (int u = 0; u < 32; ++u) s[u] += c * wp[(size_t)u*256];
    }
  }
  __align__(16) __hip_bfloat16 o[32];
  #pragma unroll
  for (int u = 0; u < 32; ++u) o[u] = __float2bfloat16(s[u] * 0.0625f);
  __hip_bfloat16* dst = kt + (size_t)(par*256 + co)*2304 + tap*256 + ciblk*32;
  #pragma unroll
  for (int v = 0; v < 4; ++v)
    reinterpret_cast<uint4*>(dst)[v] = reinterpret_cast<const uint4*>(o)[v];
}

__global__ __launch_bounds__(256) void gemm_kernel(
    const __hip_bfloat16* __restrict__ xp,
    const __hip_bfloat16* __restrict__ kt,
    const float* __restrict__ bias,
    float* __restrict__ out) {
  __shared__ __align__(16) __hip_bfloat16 sA[128*32];
  __shared__ __align__(16) __hip_bfloat16 sB[128*32];
  const int tid = threadIdx.x;
  const int bid = blockIdx.x;
  const int mt  = (bid & 7) + ((bid >> 6) << 3);
  const int nt  = (bid >> 3) & 7;
  const int b   = mt >> 7;
  const int ro  = mt & 127;
  const int n0  = nt << 7;
  const int wv = tid >> 6, ln = tid & 63, lm = ln & 15, quad = ln >> 4;
  const int wm = wv >> 1, wn = wv & 1;
  const int sr = tid >> 2;
  const int inner = (((tid & 3) ^ ((sr >> 1) & 3)) << 3);
  __hip_bfloat16* lA0 = sA + (wv*64)*8;
  __hip_bfloat16* lA1 = sA + (wv*64 + 256)*8;
  __hip_bfloat16* lB0 = sB + (wv*64)*8;
  __hip_bfloat16* lB1 = sB + (wv*64 + 256)*8;
  floatx4 acc[4][4];
  #pragma unroll
  for (int i = 0; i < 4; ++i)
    #pragma unroll
    for (int j = 0; j < 4; ++j)
      acc[i][j] = (floatx4){0.f, 0.f, 0.f, 0.f};
  const __hip_bfloat16* xb = xp + (size_t)(b*130)*130*256;
  const int cs = ((quad ^ ((lm >> 1) & 3)) << 3);
  for (int ks = 0; ks < 72; ++ks) {
    const int tap = ks >> 3;
    const int ci0 = (ks & 7) << 5;
    const int dy  = tap / 3;
    const int dx  = tap - dy*3;
    const int k0  = ks << 5;
    const __hip_bfloat16* gA = xb + (size_t)((ro + dy)*130 + dx + sr)*256 + ci0 + inner;
    gl_lds16(gA,            lA0);
    gl_lds16(gA + 64*256,   lA1);
    const __hip_bfloat16* gB = kt + (size_t)(n0 + sr)*2304 + k0 + inner;
    gl_lds16(gB,            lB0);
    gl_lds16(gB + 64*2304,  lB1);
    __syncthreads();
    bf16x8 af[4], bfr[4];
    #pragma unroll
    for (int i = 0; i < 4; ++i)
      af[i]  = *reinterpret_cast<const bf16x8*>(sA + (wm*64 + i*16 + lm)*32 + cs);
    #pragma unroll
    for (int i = 0; i < 4; ++i)
      bfr[i] = *reinterpret_cast<const bf16x8*>(sB + (wn*64 + i*16 + lm)*32 + cs);
    #pragma unroll
    for (int mi = 0; mi < 4; ++mi)
      #pragma unroll
      for (int ni = 0; ni < 4; ++ni)
        acc[mi][ni] = __builtin_amdgcn_mfma_f32_16x16x32_bf16(af[mi], bfr[ni], acc[mi][ni], 0, 0, 0);
    __syncthreads();
  }
  #pragma unroll
  for (int ni = 0; ni < 4; ++ni) {
    const int n   = n0 + wn*64 + ni*16 + lm;
    const int par = n >> 8;
    const int co  = n & 255;
    const int pr  = par >> 1;
    const int ps  = par & 1;
    const float bv = bias[co];
    const int rowo = b*256 + 2*ro + pr;
    #pragma unroll
    for (int mi = 0; mi < 4; ++mi) {
      const int so_b = wm*64 + mi*16 + (quad << 2);
      #pragma unroll
      for (int r = 0; r < 4; ++r) {
        const int so = so_b + r;
        out[((size_t)rowo*256 + (2*so + ps))*256 + co] = acc[mi][ni][r] + bv;
      }
    }
  }
}

extern "C" void kernel_launch(void* const* d_in, const int* in_sizes, int n_in,
                              void* d_out, int out_size, void* d_ws, size_t ws_size,
                              hipStream_t stream) {
  const float* x    = (const float*)d_in[0];   // (4,128,128,256)
  const float* w    = (const float*)d_in[1];   // (3,3,256,256)
  const float* bias = (const float*)d_in[2];   // (256,)
  float* out = (float*)d_out;                  // (4,256,256,256)

  __hip_bfloat16* xp = (__hip_bfloat16*)d_ws;

  if (ws_size >= NEED_WS) {
    __hip_bfloat16* U  = (__hip_bfloat16*)((char*)d_ws + XP_BYTES);
    __hip_bfloat16* wq = (__hip_bfloat16*)((char*)d_ws + XP_BYTES + U_BYTES);
    pad_cast_kernel<<<8450, 256, 0, stream>>>(x, xp);
    make_wq_kernel<<<2304, 256, 0, stream>>>(w, wq);
    border_zero_kernel<<<2068, 256, 0, stream>>>(U);
    stage1_kernel<<<4224, 256, 0, stream>>>(xp, wq, U);
    fir_kernel<<<8192, 256, 0, stream>>>(U, bias, out);
  } else {
    __hip_bfloat16* kt = (__hip_bfloat16*)((char*)d_ws + XP_BYTES);
    pad_cast_kernel<<<8450, 256, 0, stream>>>(x, xp);
    make_kt_kernel<<<288, 256, 0, stream>>>(w, kt);
    gemm_kernel<<<4096, 256, 0, stream>>>(xp, kt, bias, out);
  }
}